// Round 14
// baseline (178.443 us; speedup 1.0000x reference)
//
#include <hip/hip_runtime.h>
#include <cstdint>
#include <cstddef>

#define BATCH 8
#define NPTS  8192
#define MPTS  2048
#define C1    128
#define C2    256
#define K0    384   // C1 + C2
#define O0    256
#define O1    128
#define NROWS (BATCH * NPTS)  // 65536

typedef __attribute__((ext_vector_type(8))) short bf16x8;
typedef __attribute__((ext_vector_type(4))) float f32x4;

__device__ __forceinline__ unsigned short f2b(float f) {
    union { float f; unsigned int u; } v; v.f = f;
    unsigned int u = v.u + 0x7FFFu + ((v.u >> 16) & 1u);  // RNE
    return (unsigned short)(u >> 16);
}
__device__ __forceinline__ float b2f(unsigned short h) {
    union { unsigned int u; float f; } v; v.u = ((unsigned int)h) << 16; return v.f;
}
__device__ __forceinline__ unsigned int pack2(float a, float b) {
    return (unsigned int)f2b(a) | ((unsigned int)f2b(b) << 16);
}
__device__ __forceinline__ float med3(float a, float b, float c) {
    return __builtin_amdgcn_fmed3f(a, b, c);
}

// Merge two stably-sorted triples (x = lower-global-index side) into top-3.
// Strict < everywhere => ties favor the x side (earlier index), replicating
// stable top_k semantics.
__device__ __forceinline__ void merge3(float x0, float x1, float x2,
                                       int ix0, int ix1, int ix2,
                                       float y0, float y1, float y2,
                                       int iy0, int iy1, int iy2,
                                       float& z0, float& z1, float& z2,
                                       int& iz0, int& iz1, int& iz2) {
    const bool c0 = y0 < x0;
    const bool c1a = y1 < x0;
    const bool c1b = y0 < x1;
    z0 = c0 ? y0 : x0;  iz0 = c0 ? iy0 : ix0;
    const float z1A = c1a ? y1 : x0; const int iz1A = c1a ? iy1 : ix0;
    const float z1B = c1b ? y0 : x1; const int iz1B = c1b ? iy0 : ix1;
    z1 = c0 ? z1A : z1B; iz1 = c0 ? iz1A : iz1B;
    const bool mA1c = y2 < x0;
    const bool mA2c = y1 < x1;
    const bool mB2c = y0 < x2;
    const float mA1 = mA1c ? y2 : x0; const int imA1 = mA1c ? iy2 : ix0;
    const float mA2 = mA2c ? y1 : x1; const int imA2 = mA2c ? iy1 : ix1;
    const float mB2 = mB2c ? y0 : x2; const int imB2 = mB2c ? iy0 : ix2;
    const float z2A = c1a ? mA1 : mA2; const int iz2A = c1a ? imA1 : imA2;
    const float z2B = c1b ? mA2 : mB2; const int iz2B = c1b ? imA2 : imB2;
    z2 = c0 ? z2A : z2B; iz2 = c0 ? iz2A : iz2B;
}

// ---------------------------------------------------------------------------
// FUSED kernel: phase 1 = brute-force 3-NN for this block's 128 rows
// (8 segments x 256 pts per query-pair; exact R13 semantics: -2 pow2
// pre-scale -> bit-identical distance chain; strict-< insertion; stable
// butterfly merge, lower-seg wins ties). idx/w -> LDS.
// Phase 2 = GEMM0 (MFMA bf16) with gather-interpolate A-staging (idx/w from
// LDS), B staged directly from fp32 W0 with in-staging RNE pack, fused
// column stats, LDS-staged coalesced y0 stores.
// Cross-block phase stagger lets knn's VALU work overlap other blocks'
// MFMA/mem work on the same CU (separate pipes).
// LDS: union{s2p 32.9KB | As 16KB + Bs 32KB} + idxw 3KB = 52.2KB -> 3 blk/CU.
// ---------------------------------------------------------------------------
__global__ __launch_bounds__(512) void k_gemm0(const float* __restrict__ xyz1,
                                               const float* __restrict__ xyz2,
                                               const float* __restrict__ p1,
                                               const float* __restrict__ p2,
                                               const float* __restrict__ W0f,
                                               const float* __restrict__ bias,
                                               unsigned short* __restrict__ y,
                                               float* __restrict__ ps,
                                               float* __restrict__ pq) {
    __shared__ __align__(16) char smem[49152 + 3072];
    float4*         s2p = (float4*)smem;                       // [8][257]
    unsigned short* As  = (unsigned short*)smem;               // 128*64
    unsigned short* Bs  = (unsigned short*)(smem + 16384);     // 256*64
    float*          cps = (float*)smem;                        // [2][256][2] (aliases As)
    int*            lidx = (int*)(smem + 49152);               // [128][3]
    float*          lw   = (float*)(smem + 49152 + 1536);      // [128][3]

    const int t = threadIdx.x;
    const int r0 = blockIdx.x * 128;
    const int bb = r0 >> 13;           // batch (128 rows never cross batch)

    // ================= phase 1: 3-NN =================
    for (int p = t; p < MPTS; p += 512) {
        const size_t src = ((size_t)bb * MPTS + p) * 3;
        float px = xyz2[src + 0], py = xyz2[src + 1], pz = xyz2[src + 2];
        float sy = __fadd_rn(__fadd_rn(__fmul_rn(px, px), __fmul_rn(py, py)),
                             __fmul_rn(pz, pz));
        s2p[(p >> 8) * 257 + (p & 255)] =
            make_float4(-2.0f * px, -2.0f * py, -2.0f * pz, sy);
    }
    __syncthreads();

    {
        const int qp  = t >> 3;   // 0..63 query pair (local rows 2qp, 2qp+1)
        const int seg = t & 7;    // 0..7
        const size_t qoffA = ((size_t)r0 + qp * 2) * 3;
        const float ax = xyz1[qoffA + 0], ay = xyz1[qoffA + 1], az = xyz1[qoffA + 2];
        const float bx = xyz1[qoffA + 3], by = xyz1[qoffA + 4], bz = xyz1[qoffA + 5];
        const float sA = __fadd_rn(__fadd_rn(__fmul_rn(ax, ax), __fmul_rn(ay, ay)),
                                   __fmul_rn(az, az));
        const float sB = __fadd_rn(__fadd_rn(__fmul_rn(bx, bx), __fmul_rn(by, by)),
                                   __fmul_rn(bz, bz));

        float a0 = 3.0e38f, a1 = 3.0e38f, a2 = 3.0e38f;
        float e0 = 3.0e38f, e1 = 3.0e38f, e2 = 3.0e38f;
        int ai0 = 0, ai1 = 0, ai2 = 0;
        int bi0 = 0, bi1 = 0, bi2 = 0;
        const float4* segp = &s2p[seg * 257];
#pragma unroll 8
        for (int mm = 0; mm < 256; ++mm) {
            const float4 pp = segp[mm];   // (-2px, -2py, -2pz, pw)
            float tA = __fadd_rn(__fadd_rn(__fmul_rn(ax, pp.x), __fmul_rn(ay, pp.y)),
                                 __fmul_rn(az, pp.z));
            float dA = __fadd_rn(__fadd_rn(tA, sA), pp.w);
            float tB = __fadd_rn(__fadd_rn(__fmul_rn(bx, pp.x), __fmul_rn(by, pp.y)),
                                 __fmul_rn(bz, pp.z));
            float dB = __fadd_rn(__fadd_rn(tB, sB), pp.w);
            {
                const bool c0 = dA < a0, c1 = dA < a1, c2 = dA < a2;
                ai2 = c2 ? (c1 ? ai1 : mm) : ai2;
                ai1 = c1 ? (c0 ? ai0 : mm) : ai1;
                ai0 = c0 ? mm : ai0;
                float n2 = med3(dA, a1, a2), n1 = med3(dA, a0, a1), n0 = fminf(dA, a0);
                a2 = n2; a1 = n1; a0 = n0;
            }
            {
                const bool c0 = dB < e0, c1 = dB < e1, c2 = dB < e2;
                bi2 = c2 ? (c1 ? bi1 : mm) : bi2;
                bi1 = c1 ? (c0 ? bi0 : mm) : bi1;
                bi0 = c0 ? mm : bi0;
                float n2 = med3(dB, e1, e2), n1 = med3(dB, e0, e1), n0 = fminf(dB, e0);
                e2 = n2; e1 = n1; e0 = n0;
            }
        }
        const int m0 = seg * 256;
        ai0 += m0; ai1 += m0; ai2 += m0;
        bi0 += m0; bi1 += m0; bi2 += m0;

        // butterfly merge across the 8 seg lanes (stable, lower-seg wins)
#pragma unroll
        for (int k = 1; k <= 4; k <<= 1) {
            const bool up = (t & k) != 0;
            {
                float p0 = __shfl_xor(a0, k), p1v = __shfl_xor(a1, k), p2v = __shfl_xor(a2, k);
                int   q0 = __shfl_xor(ai0, k), q1 = __shfl_xor(ai1, k), q2 = __shfl_xor(ai2, k);
                float x0 = up ? p0 : a0, x1 = up ? p1v : a1, x2 = up ? p2v : a2;
                int  ix0 = up ? q0 : ai0, ix1 = up ? q1 : ai1, ix2 = up ? q2 : ai2;
                float y0 = up ? a0 : p0, y1 = up ? a1 : p1v, y2 = up ? a2 : p2v;
                int  iy0 = up ? ai0 : q0, iy1 = up ? ai1 : q1, iy2 = up ? ai2 : q2;
                merge3(x0, x1, x2, ix0, ix1, ix2, y0, y1, y2, iy0, iy1, iy2,
                       a0, a1, a2, ai0, ai1, ai2);
            }
            {
                float p0 = __shfl_xor(e0, k), p1v = __shfl_xor(e1, k), p2v = __shfl_xor(e2, k);
                int   q0 = __shfl_xor(bi0, k), q1 = __shfl_xor(bi1, k), q2 = __shfl_xor(bi2, k);
                float x0 = up ? p0 : e0, x1 = up ? p1v : e1, x2 = up ? p2v : e2;
                int  ix0 = up ? q0 : bi0, ix1 = up ? q1 : bi1, ix2 = up ? q2 : bi2;
                float y0 = up ? e0 : p0, y1 = up ? e1 : p1v, y2 = up ? e2 : p2v;
                int  iy0 = up ? bi0 : q0, iy1 = up ? bi1 : q1, iy2 = up ? bi2 : q2;
                merge3(x0, x1, x2, ix0, ix1, ix2, y0, y1, y2, iy0, iy1, iy2,
                       e0, e1, e2, bi0, bi1, bi2);
            }
        }

        if (seg == 0) {
            {
                const float rr0 = 1.0f / __fadd_rn(a0, 1e-8f);
                const float rr1 = 1.0f / __fadd_rn(a1, 1e-8f);
                const float rr2 = 1.0f / __fadd_rn(a2, 1e-8f);
                const float norm = __fadd_rn(__fadd_rn(rr0, rr1), rr2);
                const int lr = qp * 2;
                lidx[lr * 3 + 0] = ai0; lidx[lr * 3 + 1] = ai1; lidx[lr * 3 + 2] = ai2;
                lw[lr * 3 + 0] = rr0 / norm;
                lw[lr * 3 + 1] = rr1 / norm;
                lw[lr * 3 + 2] = rr2 / norm;
            }
            {
                const float rr0 = 1.0f / __fadd_rn(e0, 1e-8f);
                const float rr1 = 1.0f / __fadd_rn(e1, 1e-8f);
                const float rr2 = 1.0f / __fadd_rn(e2, 1e-8f);
                const float norm = __fadd_rn(__fadd_rn(rr0, rr1), rr2);
                const int lr = qp * 2 + 1;
                lidx[lr * 3 + 0] = bi0; lidx[lr * 3 + 1] = bi1; lidx[lr * 3 + 2] = bi2;
                lw[lr * 3 + 0] = rr0 / norm;
                lw[lr * 3 + 1] = rr1 / norm;
                lw[lr * 3 + 2] = rr2 / norm;
            }
        }
    }
    __syncthreads();

    // ================= phase 2: GEMM0 =================
    const int lane = t & 63;
    const int wid = t >> 6;
    const int wm = wid & 1;
    const int wn = wid >> 1;          // 0..3

    const int row_a = t >> 2;          // 0..127
    const int sa0 = (t & 3) * 2;       // 2 slots per thread
    const int row_b = t >> 1;          // 0..255
    const int sb0 = (t & 1) * 4;       // 4 slots

    const int grow = r0 + row_a;
    const int i0 = lidx[row_a * 3 + 0];
    const int i1 = lidx[row_a * 3 + 1];
    const int i2 = lidx[row_a * 3 + 2];
    const float w0 = lw[row_a * 3 + 0];
    const float w1 = lw[row_a * 3 + 1];
    const float w2 = lw[row_a * 3 + 2];
    const float* pbase = p2 + (size_t)bb * MPTS * C2;
    const float* g0 = pbase + (size_t)i0 * C2;
    const float* g1 = pbase + (size_t)i1 * C2;
    const float* g2 = pbase + (size_t)i2 * C2;
    const float* p1row = p1 + (size_t)grow * C1;

    const float* bwp = W0f + (size_t)row_b * K0;
    unsigned short* asw = &As[row_a * 64];
    unsigned short* bsw = &Bs[row_b * 64];
    const int swa = row_a & 7;
    const int swb = row_b & 7;

    f32x4 zero = {0.f, 0.f, 0.f, 0.f};
    f32x4 acc[4][4];
#pragma unroll
    for (int i = 0; i < 4; ++i)
#pragma unroll
        for (int j = 0; j < 4; ++j) acc[i][j] = zero;

    for (int kt = 0; kt < K0; kt += 64) {
        // ---- A staging (fused interp) ----
#pragma unroll
        for (int i = 0; i < 2; ++i) {
            const int slot = sa0 + i;
            const int gc = kt + slot * 8;
            uint4 ov;
            if (kt < C1) {
                const float4 u = *(const float4*)&p1row[gc];
                const float4 v = *(const float4*)&p1row[gc + 4];
                ov.x = pack2(u.x, u.y); ov.y = pack2(u.z, u.w);
                ov.z = pack2(v.x, v.y); ov.w = pack2(v.z, v.w);
            } else {
                const int cc = gc - C1;
                const float4 u0 = *(const float4*)&g0[cc];
                const float4 u1 = *(const float4*)&g0[cc + 4];
                const float4 v0 = *(const float4*)&g1[cc];
                const float4 v1 = *(const float4*)&g1[cc + 4];
                const float4 t0 = *(const float4*)&g2[cc];
                const float4 t1 = *(const float4*)&g2[cc + 4];
                const float f0 = w0 * u0.x + w1 * v0.x + w2 * t0.x;
                const float f1 = w0 * u0.y + w1 * v0.y + w2 * t0.y;
                const float f2 = w0 * u0.z + w1 * v0.z + w2 * t0.z;
                const float f3 = w0 * u0.w + w1 * v0.w + w2 * t0.w;
                const float f4 = w0 * u1.x + w1 * v1.x + w2 * t1.x;
                const float f5 = w0 * u1.y + w1 * v1.y + w2 * t1.y;
                const float f6 = w0 * u1.z + w1 * v1.z + w2 * t1.z;
                const float f7 = w0 * u1.w + w1 * v1.w + w2 * t1.w;
                ov.x = pack2(f0, f1); ov.y = pack2(f2, f3);
                ov.z = pack2(f4, f5); ov.w = pack2(f6, f7);
            }
            *(uint4*)(asw + ((slot ^ swa) * 8)) = ov;
        }
        // ---- B staging (fp32 W0 -> bf16 in-flight) ----
#pragma unroll
        for (int i = 0; i < 4; ++i) {
            const int slot = sb0 + i;
            const int gc = kt + slot * 8;
            const float4 u = *(const float4*)&bwp[gc];
            const float4 v = *(const float4*)&bwp[gc + 4];
            uint4 ov;
            ov.x = pack2(u.x, u.y); ov.y = pack2(u.z, u.w);
            ov.z = pack2(v.x, v.y); ov.w = pack2(v.z, v.w);
            *(uint4*)(bsw + (slot ^ swb) * 8) = ov;
        }
        __syncthreads();
#pragma unroll
        for (int ks = 0; ks < 2; ++ks) {
            bf16x8 af[4], bfr[4];
#pragma unroll
            for (int fr = 0; fr < 4; ++fr) {
                const int row = wm * 64 + fr * 16 + (lane & 15);
                const int slot = (ks * 4 + (lane >> 4)) ^ (row & 7);
                af[fr] = *(const bf16x8*)&As[row * 64 + slot * 8];
            }
#pragma unroll
            for (int fc = 0; fc < 4; ++fc) {
                const int row = wn * 64 + fc * 16 + (lane & 15);
                const int slot = (ks * 4 + (lane >> 4)) ^ (row & 7);
                bfr[fc] = *(const bf16x8*)&Bs[row * 64 + slot * 8];
            }
#pragma unroll
            for (int fr = 0; fr < 4; ++fr)
#pragma unroll
                for (int fc = 0; fc < 4; ++fc)
                    acc[fr][fc] = __builtin_amdgcn_mfma_f32_16x16x32_bf16(
                        af[fr], bfr[fc], acc[fr][fc], 0, 0, 0);
        }
        __syncthreads();
    }

    // ---- column stats (bf16-rounded); cps aliases dead As region ----
    float bv[4];
#pragma unroll
    for (int fc = 0; fc < 4; ++fc) {
        const int n = wn * 64 + fc * 16 + (lane & 15);   // 0..255
        bv[fc] = bias[n];
        float s = 0.0f, q = 0.0f;
#pragma unroll
        for (int fr = 0; fr < 4; ++fr) {
#pragma unroll
            for (int j = 0; j < 4; ++j) {
                const float v = b2f(f2b(acc[fr][fc][j] + bv[fc]));
                s += v;
                q = fmaf(v, v, q);
            }
        }
        s += __shfl_xor(s, 16); s += __shfl_xor(s, 32);
        q += __shfl_xor(q, 16); q += __shfl_xor(q, 32);
        if ((lane >> 4) == 0) {
            cps[((wm * 256 + n) << 1) + 0] = s;
            cps[((wm * 256 + n) << 1) + 1] = q;
        }
    }
    __syncthreads();
    if (t < 256) {
        const float s = cps[((0 * 256 + t) << 1) + 0] + cps[((1 * 256 + t) << 1) + 0];
        const float q = cps[((0 * 256 + t) << 1) + 1] + cps[((1 * 256 + t) << 1) + 1];
        const size_t o = (size_t)blockIdx.x * 256 + t;
        ps[o] = s; pq[o] = q;
    }

    // ---- y0 store via LDS (2 phases x 64 rows x 256 cols through Bs) ----
#pragma unroll
    for (int p = 0; p < 2; ++p) {
        __syncthreads();
        if (wm == p) {
#pragma unroll
            for (int fc = 0; fc < 4; ++fc) {
                const int n = wn * 64 + fc * 16 + (lane & 15);
#pragma unroll
                for (int fr = 0; fr < 4; ++fr) {
#pragma unroll
                    for (int j = 0; j < 4; ++j) {
                        const int lr = fr * 16 + (lane >> 4) * 4 + j;  // 0..63
                        Bs[lr * 256 + n] = f2b(acc[fr][fc][j] + bv[fc]);
                    }
                }
            }
        }
        __syncthreads();
        const int lr2 = t >> 3;                 // 0..63
        const int cb = (t & 7);                 // 8 chunk groups
#pragma unroll
        for (int i = 0; i < 4; ++i) {
            const int col = (cb + i * 8) * 8;   // 32 chunks of 8 cols
            *(uint4*)&y[(size_t)(r0 + p * 64 + lr2) * O0 + col] =
                *(const uint4*)&Bs[lr2 * 256 + col];
        }
    }
}

// fin0: 8 blocks x 256 thr; block handles 32 channels, 8 chunks of 64 partials.
__global__ __launch_bounds__(256) void k_fin0(const float* __restrict__ ps,
                                              const float* __restrict__ pq,
                                              const float* __restrict__ gamma,
                                              const float* __restrict__ beta,
                                              float* __restrict__ sc,
                                              float* __restrict__ sh) {
    __shared__ float red[8][32][2];
    const int tid = threadIdx.x;
    const int cl = tid & 31, qr = tid >> 5;      // 0..7 chunk
    const int c = blockIdx.x * 32 + cl;
    float s = 0.0f, q = 0.0f;
    for (int bx = qr * 64; bx < qr * 64 + 64; ++bx) {
        s += ps[(size_t)bx * 256 + c];
        q += pq[(size_t)bx * 256 + c];
    }
    red[qr][cl][0] = s; red[qr][cl][1] = q;
    __syncthreads();
    if (tid < 32) {
        float ss = 0.0f, qq = 0.0f;
#pragma unroll
        for (int k = 0; k < 8; ++k) { ss += red[k][tid][0]; qq += red[k][tid][1]; }
        const int ch = blockIdx.x * 32 + tid;
        const float mean = ss * (1.0f / NROWS);
        const float var = qq * (1.0f / NROWS) - mean * mean;
        const float rs = rsqrtf(var + 1e-5f);
        const float scale = gamma[ch] * rs;
        sc[ch] = scale;
        sh[ch] = beta[ch] - mean * scale;
    }
}

// ---------------------------------------------------------------------------
// GEMM1 (MFMA bf16) + fused column-stats partials; BN0+ReLU on A-load.
// B staged directly from fp32 W1. Writes y1 as bf16 via LDS-staged stores.
// ---------------------------------------------------------------------------
__global__ __launch_bounds__(256) void k_gemm1(const unsigned short* __restrict__ y0,
                                               const float* __restrict__ W1f,
                                               const float* __restrict__ bias,
                                               const float* __restrict__ sc,
                                               const float* __restrict__ sh,
                                               unsigned short* __restrict__ y1,
                                               float* __restrict__ ps,
                                               float* __restrict__ pq) {
    __shared__ __align__(16) unsigned short As[128 * 64];
    __shared__ __align__(16) unsigned short Bs[128 * 64];   // 16 KB (reused)
    __shared__ float cps[2][128][2];
    const int t = threadIdx.x;
    const int r0 = blockIdx.x * 128;
    const int lane = t & 63;
    const int wm = (t >> 6) & 1;
    const int wn = (t >> 6) >> 1;
    const int row_s = t >> 1;
    const int slot4 = (t & 1) * 4;
    const int sw = row_s & 7;

    const unsigned short* aptr = y0 + (size_t)(r0 + row_s) * O0;
    const float* bptr = W1f + (size_t)row_s * O0;
    unsigned short* asw = &As[row_s * 64];
    unsigned short* bsw = &Bs[row_s * 64];

    f32x4 zero = {0.f, 0.f, 0.f, 0.f};
    f32x4 acc[4][4];
#pragma unroll
    for (int i = 0; i < 4; ++i)
#pragma unroll
        for (int j = 0; j < 4; ++j) acc[i][j] = zero;

    for (int kt = 0; kt < O0; kt += 64) {
#pragma unroll
        for (int i = 0; i < 4; ++i) {
            const int slot = slot4 + i;
            const int ssw = slot ^ sw;
            const int c0 = kt + slot * 8;
            uint4 av = *(const uint4*)(aptr + c0);
            const float4 s0 = *(const float4*)&sc[c0];
            const float4 s1 = *(const float4*)&sc[c0 + 4];
            const float4 h0 = *(const float4*)&sh[c0];
            const float4 h1 = *(const float4*)&sh[c0 + 4];
            uint4 ov;
            {
                float v0 = b2f(av.x & 0xffff), v1 = b2f(av.x >> 16);
                ov.x = pack2(fmaxf(fmaf(v0, s0.x, h0.x), 0.f),
                             fmaxf(fmaf(v1, s0.y, h0.y), 0.f));
                float v2 = b2f(av.y & 0xffff), v3 = b2f(av.y >> 16);
                ov.y = pack2(fmaxf(fmaf(v2, s0.z, h0.z), 0.f),
                             fmaxf(fmaf(v3, s0.w, h0.w), 0.f));
                float v4 = b2f(av.z & 0xffff), v5 = b2f(av.z >> 16);
                ov.z = pack2(fmaxf(fmaf(v4, s1.x, h1.x), 0.f),
                             fmaxf(fmaf(v5, s1.y, h1.y), 0.f));
                float v6 = b2f(av.w & 0xffff), v7 = b2f(av.w >> 16);
                ov.w = pack2(fmaxf(fmaf(v6, s1.z, h1.z), 0.f),
                             fmaxf(fmaf(v7, s1.w, h1.w), 0.f));
            }
            *(uint4*)(asw + ssw * 8) = ov;
            const float4 u = *(const float4*)&bptr[c0];
            const float4 v = *(const float4*)&bptr[c0 + 4];
            uint4 bvv;
            bvv.x = pack2(u.x, u.y); bvv.y = pack2(u.z, u.w);
            bvv.z = pack2(v.x, v.y); bvv.w = pack2(v.z, v.w);
            *(uint4*)(bsw + ssw * 8) = bvv;
        }
        __syncthreads();
#pragma unroll
        for (int ks = 0; ks < 2; ++ks) {
            bf16x8 af[4], bfr[4];
#pragma unroll
            for (int fr = 0; fr < 4; ++fr) {
                const int row = wm * 64 + fr * 16 + (lane & 15);
                const int slot = (ks * 4 + (lane >> 4)) ^ (row & 7);
                af[fr] = *(const bf16x8*)&As[row * 64 + slot * 8];
            }
#pragma unroll
            for (int fc = 0; fc < 4; ++fc) {
                const int row = wn * 64 + fc * 16 + (lane & 15);
                const int slot = (ks * 4 + (lane >> 4)) ^ (row & 7);
                bfr[fc] = *(const bf16x8*)&Bs[row * 64 + slot * 8];
            }
#pragma unroll
            for (int fr = 0; fr < 4; ++fr)
#pragma unroll
                for (int fc = 0; fc < 4; ++fc)
                    acc[fr][fc] = __builtin_amdgcn_mfma_f32_16x16x32_bf16(
                        af[fr], bfr[fc], acc[fr][fc], 0, 0, 0);
        }
        __syncthreads();
    }

    // ---- column stats (bf16-rounded, consistent with stored y1) ----
    float bvr[4];
#pragma unroll
    for (int fc = 0; fc < 4; ++fc) {
        const int cl = wn * 64 + fc * 16 + (lane & 15);
        bvr[fc] = bias[cl];
        float s = 0.0f, q = 0.0f;
#pragma unroll
        for (int fr = 0; fr < 4; ++fr) {
#pragma unroll
            for (int j = 0; j < 4; ++j) {
                const float v = b2f(f2b(acc[fr][fc][j] + bvr[fc]));
                s += v;
                q = fmaf(v, v, q);
            }
        }
        s += __shfl_xor(s, 16); s += __shfl_xor(s, 32);
        q += __shfl_xor(q, 16); q += __shfl_xor(q, 32);
        if ((lane >> 4) == 0) { cps[wm][cl][0] = s; cps[wm][cl][1] = q; }
    }
    __syncthreads();
    if (t < 128) {
        ps[(size_t)blockIdx.x * 128 + t] = cps[0][t][0] + cps[1][t][0];
        pq[(size_t)blockIdx.x * 128 + t] = cps[0][t][1] + cps[1][t][1];
    }

    // ---- y1 store via LDS (2 phases x 64 rows x 128 cols through Bs) ----
#pragma unroll
    for (int p = 0; p < 2; ++p) {
        __syncthreads();
        if (wm == p) {
#pragma unroll
            for (int fc = 0; fc < 4; ++fc) {
                const int cl = wn * 64 + fc * 16 + (lane & 15);
#pragma unroll
                for (int fr = 0; fr < 4; ++fr) {
#pragma unroll
                    for (int j = 0; j < 4; ++j) {
                        const int lr = fr * 16 + (lane >> 4) * 4 + j;  // 0..63
                        Bs[lr * 128 + cl] = f2b(acc[fr][fc][j] + bvr[fc]);
                    }
                }
            }
        }
        __syncthreads();
        const int lr2 = t >> 2;                 // 0..63
        const int cb = (t & 3);                 // 4 chunk groups
#pragma unroll
        for (int i = 0; i < 4; ++i) {
            const int col = (cb + i * 4) * 8;   // 16 chunks of 8 cols
            *(uint4*)&y1[(size_t)(r0 + p * 64 + lr2) * O1 + col] =
                *(const uint4*)&Bs[lr2 * 128 + col];
        }
    }
}

// fin1: 8 blocks x 128 thr; block handles 16 channels, 8 chunks of 64 partials.
__global__ __launch_bounds__(128) void k_fin1(const float* __restrict__ ps,
                                              const float* __restrict__ pq,
                                              const float* __restrict__ gamma,
                                              const float* __restrict__ beta,
                                              float* __restrict__ sc,
                                              float* __restrict__ sh) {
    __shared__ float red[8][16][2];
    const int tid = threadIdx.x;
    const int cl = tid & 15, qr = tid >> 4;      // 0..7 chunk
    const int c = blockIdx.x * 16 + cl;
    float s = 0.0f, q = 0.0f;
    for (int bx = qr * 64; bx < qr * 64 + 64; ++bx) {
        s += ps[(size_t)bx * 128 + c];
        q += pq[(size_t)bx * 128 + c];
    }
    red[qr][cl][0] = s; red[qr][cl][1] = q;
    __syncthreads();
    if (tid < 16) {
        float ss = 0.0f, qq = 0.0f;
#pragma unroll
        for (int k = 0; k < 8; ++k) { ss += red[k][tid][0]; qq += red[k][tid][1]; }
        const int ch = blockIdx.x * 16 + tid;
        const float mean = ss * (1.0f / NROWS);
        const float var = qq * (1.0f / NROWS) - mean * mean;
        const float rs = rsqrtf(var + 1e-5f);
        const float scale = gamma[ch] * rs;
        sc[ch] = scale;
        sh[ch] = beta[ch] - mean * scale;
    }
}

// BN + ReLU: read bf16 y1, write fp32 out. 8 elems/thread.
__global__ __launch_bounds__(256) void k_bnrelu(const unsigned short* __restrict__ y1,
                                                const float* __restrict__ sc,
                                                const float* __restrict__ sh,
                                                float* __restrict__ out) {
    const int e8 = blockIdx.x * 256 + threadIdx.x;
    const int c = (e8 & 15) << 3;   // O1=128 -> col base of this 8-chunk
    const uint4 v = ((const uint4*)y1)[e8];
    float4 lo, hi;
    const float4 s0 = *(const float4*)&sc[c];
    const float4 s1 = *(const float4*)&sc[c + 4];
    const float4 h0 = *(const float4*)&sh[c];
    const float4 h1 = *(const float4*)&sh[c + 4];
    lo.x = fmaxf(fmaf(b2f(v.x & 0xffff), s0.x, h0.x), 0.0f);
    lo.y = fmaxf(fmaf(b2f(v.x >> 16),    s0.y, h0.y), 0.0f);
    lo.z = fmaxf(fmaf(b2f(v.y & 0xffff), s0.z, h0.z), 0.0f);
    lo.w = fmaxf(fmaf(b2f(v.y >> 16),    s0.w, h0.w), 0.0f);
    hi.x = fmaxf(fmaf(b2f(v.z & 0xffff), s1.x, h1.x), 0.0f);
    hi.y = fmaxf(fmaf(b2f(v.z >> 16),    s1.y, h1.y), 0.0f);
    hi.z = fmaxf(fmaf(b2f(v.w & 0xffff), s1.z, h1.z), 0.0f);
    hi.w = fmaxf(fmaf(b2f(v.w >> 16),    s1.w, h1.w), 0.0f);
    ((float4*)out)[(size_t)e8 * 2 + 0] = lo;
    ((float4*)out)[(size_t)e8 * 2 + 1] = hi;
}

// ---------------------------------------------------------------------------
extern "C" void kernel_launch(void* const* d_in, const int* in_sizes, int n_in,
                              void* d_out, int out_size, void* d_ws, size_t ws_size,
                              hipStream_t stream) {
    const float* xyz1    = (const float*)d_in[0];
    const float* xyz2    = (const float*)d_in[1];
    const float* points1 = (const float*)d_in[2];
    const float* points2 = (const float*)d_in[3];
    const float* W0      = (const float*)d_in[4];
    const float* b0      = (const float*)d_in[5];
    const float* gamma0  = (const float*)d_in[6];
    const float* beta0   = (const float*)d_in[7];
    const float* W1      = (const float*)d_in[8];
    const float* b1      = (const float*)d_in[9];
    const float* gamma1  = (const float*)d_in[10];
    const float* beta1   = (const float*)d_in[11];
    float* out = (float*)d_out;

    char* ws = (char*)d_ws;
    unsigned short* y0  = (unsigned short*)(ws + 0);            // 33,554,432 B
    unsigned short* y1b = (unsigned short*)(ws + 33554432ull);  // 16,777,216 B
    float*          ps0 = (float*)         (ws + 50331648ull);  //    524,288 B
    float*          pq0 = (float*)         (ws + 50855936ull);  //    524,288 B
    float*          ps1 = (float*)         (ws + 51380224ull);  //    262,144 B
    float*          pq1 = (float*)         (ws + 51642368ull);  //    262,144 B
    float*          sc0 = (float*)         (ws + 51904512ull);
    float*          sh0 = (float*)         (ws + 51905536ull);
    float*          sc1 = (float*)         (ws + 51906560ull);
    float*          sh1 = (float*)         (ws + 51907072ull);

    hipLaunchKernelGGL(k_gemm0, dim3(NROWS / 128), dim3(512), 0, stream,
                       xyz1, xyz2, points1, points2, W0, b0, y0, ps0, pq0);
    hipLaunchKernelGGL(k_fin0, dim3(8), dim3(256), 0, stream,
                       ps0, pq0, gamma0, beta0, sc0, sh0);
    hipLaunchKernelGGL(k_gemm1, dim3(NROWS / 128), dim3(256), 0, stream,
                       y0, W1, b1, sc0, sh0, y1b, ps1, pq1);
    hipLaunchKernelGGL(k_fin1, dim3(8), dim3(128), 0, stream,
                       ps1, pq1, gamma1, beta1, sc1, sh1);
    hipLaunchKernelGGL(k_bnrelu, dim3(NROWS * O1 / 8 / 256), dim3(256), 0, stream,
                       y1b, sc1, sh1, out);
}

// Round 15
// 156.500 us; speedup vs baseline: 1.1402x; 1.1402x over previous
//
#include <hip/hip_runtime.h>
#include <cstdint>
#include <cstddef>

#define BATCH 8
#define NPTS  8192
#define MPTS  2048
#define C1    128
#define C2    256
#define K0    384   // C1 + C2
#define O0    256
#define O1    128
#define NROWS (BATCH * NPTS)  // 65536

typedef __attribute__((ext_vector_type(8))) short bf16x8;
typedef __attribute__((ext_vector_type(4))) float f32x4;

__device__ __forceinline__ unsigned short f2b(float f) {
    union { float f; unsigned int u; } v; v.f = f;
    unsigned int u = v.u + 0x7FFFu + ((v.u >> 16) & 1u);  // RNE
    return (unsigned short)(u >> 16);
}
__device__ __forceinline__ float b2f(unsigned short h) {
    union { unsigned int u; float f; } v; v.u = ((unsigned int)h) << 16; return v.f;
}
__device__ __forceinline__ unsigned int pack2(float a, float b) {
    return (unsigned int)f2b(a) | ((unsigned int)f2b(b) << 16);
}
__device__ __forceinline__ float med3(float a, float b, float c) {
    return __builtin_amdgcn_fmed3f(a, b, c);
}

// Merge two stably-sorted triples (x = lower-global-index side) into top-3.
// Strict < everywhere => ties favor the x side (earlier index), replicating
// stable top_k semantics.
__device__ __forceinline__ void merge3(float x0, float x1, float x2,
                                       int ix0, int ix1, int ix2,
                                       float y0, float y1, float y2,
                                       int iy0, int iy1, int iy2,
                                       float& z0, float& z1, float& z2,
                                       int& iz0, int& iz1, int& iz2) {
    const bool c0 = y0 < x0;
    const bool c1a = y1 < x0;
    const bool c1b = y0 < x1;
    z0 = c0 ? y0 : x0;  iz0 = c0 ? iy0 : ix0;
    const float z1A = c1a ? y1 : x0; const int iz1A = c1a ? iy1 : ix0;
    const float z1B = c1b ? y0 : x1; const int iz1B = c1b ? iy0 : ix1;
    z1 = c0 ? z1A : z1B; iz1 = c0 ? iz1A : iz1B;
    const bool mA1c = y2 < x0;
    const bool mA2c = y1 < x1;
    const bool mB2c = y0 < x2;
    const float mA1 = mA1c ? y2 : x0; const int imA1 = mA1c ? iy2 : ix0;
    const float mA2 = mA2c ? y1 : x1; const int imA2 = mA2c ? iy1 : ix1;
    const float mB2 = mB2c ? y0 : x2; const int imB2 = mB2c ? iy0 : ix2;
    const float z2A = c1a ? mA1 : mA2; const int iz2A = c1a ? imA1 : imA2;
    const float z2B = c1b ? mA2 : mB2; const int iz2B = c1b ? imA2 : imB2;
    z2 = c0 ? z2A : z2B; iz2 = c0 ? iz2A : iz2B;
}

// ---------------------------------------------------------------------------
// Kernel 1: brute-force 3-NN + inverse-distance weights (+ fused weight cvt).
// 1024 blocks x 512 thr = 32 query-pairs x 16 segments (64 queries/block).
// LDS stores (-2px, -2py, -2pz, |p|^2) (exact pow2 pre-scale -> distance
// bit-identical to reference chain). Hot loop tracks SEGMENT-LOCAL index mm
// (m0 added once after the loop). Stride 129 float4s -> 2-way bank aliasing
// (free). shfl_xor butterfly merge (stable, lower-seg wins ties).
// Prologue converts W0/W1 fp32->bf16 (1 elem for gid<131072; overlaps the
// xyz2 LDS staging) -- saves the separate k_cvt launch.
// ---------------------------------------------------------------------------
__global__ __launch_bounds__(512) void k_knn(const float* __restrict__ xyz1,
                                             const float* __restrict__ xyz2,
                                             int* __restrict__ idxo,
                                             float* __restrict__ wo,
                                             const float* __restrict__ W0,
                                             const float* __restrict__ W1,
                                             unsigned short* __restrict__ Wb0,
                                             unsigned short* __restrict__ Wb1) {
    __shared__ float4 s2p[16][129];   // 33,024 B

    const int b = blockIdx.x >> 7;              // 128 blocks per batch
    const int qbase = (blockIdx.x & 127) * 64;

    // fused weight conversion: gid < 98304 -> Wb0, < 131072 -> Wb1
    {
        const int gid = blockIdx.x * 512 + threadIdx.x;
        if (gid < O0 * K0) {
            Wb0[gid] = f2b(W0[gid]);
        } else if (gid < O0 * K0 + O1 * O0) {
            const int g2 = gid - O0 * K0;
            Wb1[g2] = f2b(W1[g2]);
        }
    }

    for (int p = threadIdx.x; p < MPTS; p += 512) {
        const size_t src = ((size_t)b * MPTS + p) * 3;
        float px = xyz2[src + 0], py = xyz2[src + 1], pz = xyz2[src + 2];
        float sy = __fadd_rn(__fadd_rn(__fmul_rn(px, px), __fmul_rn(py, py)),
                             __fmul_rn(pz, pz));
        s2p[p >> 7][p & 127] = make_float4(-2.0f * px, -2.0f * py, -2.0f * pz, sy);
    }
    __syncthreads();

    const int qp  = threadIdx.x >> 4;   // 0..31 query pair
    const int seg = threadIdx.x & 15;   // 0..15
    const int nA = qbase + qp * 2;
    const size_t qoffA = ((size_t)b * NPTS + nA) * 3;
    const float ax = xyz1[qoffA + 0], ay = xyz1[qoffA + 1], az = xyz1[qoffA + 2];
    const float bx = xyz1[qoffA + 3], by = xyz1[qoffA + 4], bz = xyz1[qoffA + 5];
    const float sA = __fadd_rn(__fadd_rn(__fmul_rn(ax, ax), __fmul_rn(ay, ay)),
                               __fmul_rn(az, az));
    const float sB = __fadd_rn(__fadd_rn(__fmul_rn(bx, bx), __fmul_rn(by, by)),
                               __fmul_rn(bz, bz));

    float a0 = 3.0e38f, a1 = 3.0e38f, a2 = 3.0e38f;
    float e0 = 3.0e38f, e1 = 3.0e38f, e2 = 3.0e38f;
    int ai0 = 0, ai1 = 0, ai2 = 0;
    int bi0 = 0, bi1 = 0, bi2 = 0;
    const int m0 = seg * 128;
    const float4* segp = &s2p[seg][0];
#pragma unroll 8
    for (int mm = 0; mm < 128; ++mm) {
        const float4 pp = segp[mm];   // (-2px, -2py, -2pz, pw)
        float tA = __fadd_rn(__fadd_rn(__fmul_rn(ax, pp.x), __fmul_rn(ay, pp.y)),
                             __fmul_rn(az, pp.z));
        float dA = __fadd_rn(__fadd_rn(tA, sA), pp.w);
        float tB = __fadd_rn(__fadd_rn(__fmul_rn(bx, pp.x), __fmul_rn(by, pp.y)),
                             __fmul_rn(bz, pp.z));
        float dB = __fadd_rn(__fadd_rn(tB, sB), pp.w);
        {
            const bool c0 = dA < a0, c1 = dA < a1, c2 = dA < a2;
            ai2 = c2 ? (c1 ? ai1 : mm) : ai2;
            ai1 = c1 ? (c0 ? ai0 : mm) : ai1;
            ai0 = c0 ? mm : ai0;
            float n2 = med3(dA, a1, a2), n1 = med3(dA, a0, a1), n0 = fminf(dA, a0);
            a2 = n2; a1 = n1; a0 = n0;
        }
        {
            const bool c0 = dB < e0, c1 = dB < e1, c2 = dB < e2;
            bi2 = c2 ? (c1 ? bi1 : mm) : bi2;
            bi1 = c1 ? (c0 ? bi0 : mm) : bi1;
            bi0 = c0 ? mm : bi0;
            float n2 = med3(dB, e1, e2), n1 = med3(dB, e0, e1), n0 = fminf(dB, e0);
            e2 = n2; e1 = n1; e0 = n0;
        }
    }
    // globalize segment-local indices (slots always filled for 128 >= 3)
    ai0 += m0; ai1 += m0; ai2 += m0;
    bi0 += m0; bi1 += m0; bi2 += m0;

    // In-wave butterfly merge across the 16 seg lanes (stable, lower-seg wins).
#pragma unroll
    for (int k = 1; k <= 8; k <<= 1) {
        const bool up = (threadIdx.x & k) != 0;
        {
            float p0 = __shfl_xor(a0, k), p1 = __shfl_xor(a1, k), p2 = __shfl_xor(a2, k);
            int   q0 = __shfl_xor(ai0, k), q1 = __shfl_xor(ai1, k), q2 = __shfl_xor(ai2, k);
            float x0 = up ? p0 : a0, x1 = up ? p1 : a1, x2 = up ? p2 : a2;
            int  ix0 = up ? q0 : ai0, ix1 = up ? q1 : ai1, ix2 = up ? q2 : ai2;
            float y0 = up ? a0 : p0, y1 = up ? a1 : p1, y2 = up ? a2 : p2;
            int  iy0 = up ? ai0 : q0, iy1 = up ? ai1 : q1, iy2 = up ? ai2 : q2;
            merge3(x0, x1, x2, ix0, ix1, ix2, y0, y1, y2, iy0, iy1, iy2,
                   a0, a1, a2, ai0, ai1, ai2);
        }
        {
            float p0 = __shfl_xor(e0, k), p1 = __shfl_xor(e1, k), p2 = __shfl_xor(e2, k);
            int   q0 = __shfl_xor(bi0, k), q1 = __shfl_xor(bi1, k), q2 = __shfl_xor(bi2, k);
            float x0 = up ? p0 : e0, x1 = up ? p1 : e1, x2 = up ? p2 : e2;
            int  ix0 = up ? q0 : bi0, ix1 = up ? q1 : bi1, ix2 = up ? q2 : bi2;
            float y0 = up ? e0 : p0, y1 = up ? e1 : p1, y2 = up ? e2 : p2;
            int  iy0 = up ? bi0 : q0, iy1 = up ? bi1 : q1, iy2 = up ? bi2 : q2;
            merge3(x0, x1, x2, ix0, ix1, ix2, y0, y1, y2, iy0, iy1, iy2,
                   e0, e1, e2, bi0, bi1, bi2);
        }
    }

    if (seg == 0) {
        {
            const float r0 = 1.0f / __fadd_rn(a0, 1e-8f);
            const float r1 = 1.0f / __fadd_rn(a1, 1e-8f);
            const float r2 = 1.0f / __fadd_rn(a2, 1e-8f);
            const float norm = __fadd_rn(__fadd_rn(r0, r1), r2);
            const size_t row = (size_t)b * NPTS + nA;
            idxo[row * 3 + 0] = ai0; idxo[row * 3 + 1] = ai1; idxo[row * 3 + 2] = ai2;
            wo[row * 3 + 0] = r0 / norm;
            wo[row * 3 + 1] = r1 / norm;
            wo[row * 3 + 2] = r2 / norm;
        }
        {
            const float r0 = 1.0f / __fadd_rn(e0, 1e-8f);
            const float r1 = 1.0f / __fadd_rn(e1, 1e-8f);
            const float r2 = 1.0f / __fadd_rn(e2, 1e-8f);
            const float norm = __fadd_rn(__fadd_rn(r0, r1), r2);
            const size_t row = (size_t)b * NPTS + nA + 1;
            idxo[row * 3 + 0] = bi0; idxo[row * 3 + 1] = bi1; idxo[row * 3 + 2] = bi2;
            wo[row * 3 + 0] = r0 / norm;
            wo[row * 3 + 1] = r1 / norm;
            wo[row * 3 + 2] = r2 / norm;
        }
    }
}

// ---------------------------------------------------------------------------
// GEMM0 (MFMA bf16) with FUSED gather-interpolate A-staging + column stats.
// Block tile 128x256 (grid 512), 512 thr = 8 waves (2x4), wave 64x64, BK=64.
// y0 stores staged through LDS (Bs reuse, 2 phases of 64 rows) for coalesced
// 16B stores.
// ---------------------------------------------------------------------------
__global__ __launch_bounds__(512) void k_gemm0(const float* __restrict__ p1,
                                               const float* __restrict__ p2,
                                               const int* __restrict__ idx,
                                               const float* __restrict__ w,
                                               const unsigned short* __restrict__ Wb,
                                               const float* __restrict__ bias,
                                               unsigned short* __restrict__ y,
                                               float* __restrict__ ps,
                                               float* __restrict__ pq) {
    __shared__ __align__(16) unsigned short As[128 * 64];  // 16 KB
    __shared__ __align__(16) unsigned short Bs[256 * 64];  // 32 KB (reused)
    __shared__ float cps[2][256][2];                       //  4 KB
    const int t = threadIdx.x;
    const int r0 = blockIdx.x * 128;
    const int lane = t & 63;
    const int wid = t >> 6;
    const int wm = wid & 1;
    const int wn = wid >> 1;          // 0..3

    const int row_a = t >> 2;          // 0..127 (4 threads per row)
    const int sa0 = (t & 3) * 2;       // 2 slots (16 cols) per thread
    const int row_b = t >> 1;          // 0..255
    const int sb0 = (t & 1) * 4;       // 4 slots

    const int grow = r0 + row_a;
    const int bb = grow >> 13;
    const int i0 = idx[grow * 3 + 0];
    const int i1 = idx[grow * 3 + 1];
    const int i2 = idx[grow * 3 + 2];
    const float w0 = w[grow * 3 + 0];
    const float w1 = w[grow * 3 + 1];
    const float w2 = w[grow * 3 + 2];
    const float* pbase = p2 + (size_t)bb * MPTS * C2;
    const float* g0 = pbase + (size_t)i0 * C2;
    const float* g1 = pbase + (size_t)i1 * C2;
    const float* g2 = pbase + (size_t)i2 * C2;
    const float* p1row = p1 + (size_t)grow * C1;

    const unsigned short* bptr = Wb + (size_t)row_b * K0;
    unsigned short* asw = &As[row_a * 64];
    unsigned short* bsw = &Bs[row_b * 64];
    const int swa = row_a & 7;
    const int swb = row_b & 7;

    f32x4 zero = {0.f, 0.f, 0.f, 0.f};
    f32x4 acc[4][4];
#pragma unroll
    for (int i = 0; i < 4; ++i)
#pragma unroll
        for (int j = 0; j < 4; ++j) acc[i][j] = zero;

    for (int kt = 0; kt < K0; kt += 64) {
        // ---- A staging (fused interp) ----
#pragma unroll
        for (int i = 0; i < 2; ++i) {
            const int slot = sa0 + i;
            const int gc = kt + slot * 8;
            uint4 ov;
            if (kt < C1) {
                const float4 u = *(const float4*)&p1row[gc];
                const float4 v = *(const float4*)&p1row[gc + 4];
                ov.x = pack2(u.x, u.y); ov.y = pack2(u.z, u.w);
                ov.z = pack2(v.x, v.y); ov.w = pack2(v.z, v.w);
            } else {
                const int cc = gc - C1;
                const float4 u0 = *(const float4*)&g0[cc];
                const float4 u1 = *(const float4*)&g0[cc + 4];
                const float4 v0 = *(const float4*)&g1[cc];
                const float4 v1 = *(const float4*)&g1[cc + 4];
                const float4 t0 = *(const float4*)&g2[cc];
                const float4 t1 = *(const float4*)&g2[cc + 4];
                const float f0 = w0 * u0.x + w1 * v0.x + w2 * t0.x;
                const float f1 = w0 * u0.y + w1 * v0.y + w2 * t0.y;
                const float f2 = w0 * u0.z + w1 * v0.z + w2 * t0.z;
                const float f3 = w0 * u0.w + w1 * v0.w + w2 * t0.w;
                const float f4 = w0 * u1.x + w1 * v1.x + w2 * t1.x;
                const float f5 = w0 * u1.y + w1 * v1.y + w2 * t1.y;
                const float f6 = w0 * u1.z + w1 * v1.z + w2 * t1.z;
                const float f7 = w0 * u1.w + w1 * v1.w + w2 * t1.w;
                ov.x = pack2(f0, f1); ov.y = pack2(f2, f3);
                ov.z = pack2(f4, f5); ov.w = pack2(f6, f7);
            }
            *(uint4*)(asw + ((slot ^ swa) * 8)) = ov;
        }
        // ---- B staging ----
#pragma unroll
        for (int i = 0; i < 4; ++i) {
            const int slot = sb0 + i;
            *(uint4*)(bsw + (slot ^ swb) * 8) = *(const uint4*)(bptr + kt + slot * 8);
        }
        __syncthreads();
#pragma unroll
        for (int ks = 0; ks < 2; ++ks) {
            bf16x8 af[4], bfr[4];
#pragma unroll
            for (int fr = 0; fr < 4; ++fr) {
                const int row = wm * 64 + fr * 16 + (lane & 15);
                const int slot = (ks * 4 + (lane >> 4)) ^ (row & 7);
                af[fr] = *(const bf16x8*)&As[row * 64 + slot * 8];
            }
#pragma unroll
            for (int fc = 0; fc < 4; ++fc) {
                const int row = wn * 64 + fc * 16 + (lane & 15);
                const int slot = (ks * 4 + (lane >> 4)) ^ (row & 7);
                bfr[fc] = *(const bf16x8*)&Bs[row * 64 + slot * 8];
            }
#pragma unroll
            for (int fr = 0; fr < 4; ++fr)
#pragma unroll
                for (int fc = 0; fc < 4; ++fc)
                    acc[fr][fc] = __builtin_amdgcn_mfma_f32_16x16x32_bf16(
                        af[fr], bfr[fc], acc[fr][fc], 0, 0, 0);
        }
        __syncthreads();
    }

    // ---- column stats (from bf16-rounded values) ----
    float bv[4];
#pragma unroll
    for (int fc = 0; fc < 4; ++fc) {
        const int n = wn * 64 + fc * 16 + (lane & 15);   // 0..255
        bv[fc] = bias[n];
        float s = 0.0f, q = 0.0f;
#pragma unroll
        for (int fr = 0; fr < 4; ++fr) {
#pragma unroll
            for (int j = 0; j < 4; ++j) {
                const float v = b2f(f2b(acc[fr][fc][j] + bv[fc]));
                s += v;
                q = fmaf(v, v, q);
            }
        }
        s += __shfl_xor(s, 16); s += __shfl_xor(s, 32);
        q += __shfl_xor(q, 16); q += __shfl_xor(q, 32);
        if ((lane >> 4) == 0) { cps[wm][n][0] = s; cps[wm][n][1] = q; }
    }
    __syncthreads();
    if (t < 256) {
        const float s = cps[0][t][0] + cps[1][t][0];
        const float q = cps[0][t][1] + cps[1][t][1];
        const size_t o = (size_t)blockIdx.x * 256 + t;
        ps[o] = s; pq[o] = q;
    }

    // ---- y0 store via LDS (2 phases x 64 rows x 256 cols = 32 KB in Bs) ----
#pragma unroll
    for (int p = 0; p < 2; ++p) {
        __syncthreads();
        if (wm == p) {
#pragma unroll
            for (int fc = 0; fc < 4; ++fc) {
                const int n = wn * 64 + fc * 16 + (lane & 15);
#pragma unroll
                for (int fr = 0; fr < 4; ++fr) {
#pragma unroll
                    for (int j = 0; j < 4; ++j) {
                        const int lr = fr * 16 + (lane >> 4) * 4 + j;  // 0..63
                        Bs[lr * 256 + n] = f2b(acc[fr][fc][j] + bv[fc]);
                    }
                }
            }
        }
        __syncthreads();
        const int lr2 = t >> 3;                 // 0..63
        const int cb = (t & 7);                 // 8 chunk groups
#pragma unroll
        for (int i = 0; i < 4; ++i) {
            const int col = (cb + i * 8) * 8;   // 32 chunks of 8 cols
            *(uint4*)&y[(size_t)(r0 + p * 64 + lr2) * O0 + col] =
                *(const uint4*)&Bs[lr2 * 256 + col];
        }
    }
}

// fin0: 8 blocks x 256 thr; block handles 32 channels, 8 chunks of 64 partials.
__global__ __launch_bounds__(256) void k_fin0(const float* __restrict__ ps,
                                              const float* __restrict__ pq,
                                              const float* __restrict__ gamma,
                                              const float* __restrict__ beta,
                                              float* __restrict__ sc,
                                              float* __restrict__ sh) {
    __shared__ float red[8][32][2];
    const int tid = threadIdx.x;
    const int cl = tid & 31, qr = tid >> 5;      // 0..7 chunk
    const int c = blockIdx.x * 32 + cl;
    float s = 0.0f, q = 0.0f;
    for (int bx = qr * 64; bx < qr * 64 + 64; ++bx) {
        s += ps[(size_t)bx * 256 + c];
        q += pq[(size_t)bx * 256 + c];
    }
    red[qr][cl][0] = s; red[qr][cl][1] = q;
    __syncthreads();
    if (tid < 32) {
        float ss = 0.0f, qq = 0.0f;
#pragma unroll
        for (int k = 0; k < 8; ++k) { ss += red[k][tid][0]; qq += red[k][tid][1]; }
        const int ch = blockIdx.x * 32 + tid;
        const float mean = ss * (1.0f / NROWS);
        const float var = qq * (1.0f / NROWS) - mean * mean;
        const float rs = rsqrtf(var + 1e-5f);
        const float scale = gamma[ch] * rs;
        sc[ch] = scale;
        sh[ch] = beta[ch] - mean * scale;
    }
}

// ---------------------------------------------------------------------------
// GEMM1 (MFMA bf16) + fused column-stats partials; BN0+ReLU on A-load.
// Block tile 128x128 (grid 512), 256 thr. Writes y1 as bf16 via LDS-staged
// coalesced stores (2 phases of 64 rows through Bs).
// ---------------------------------------------------------------------------
__global__ __launch_bounds__(256) void k_gemm1(const unsigned short* __restrict__ y0,
                                               const unsigned short* __restrict__ Wb,
                                               const float* __restrict__ bias,
                                               const float* __restrict__ sc,
                                               const float* __restrict__ sh,
                                               unsigned short* __restrict__ y1,
                                               float* __restrict__ ps,
                                               float* __restrict__ pq) {
    __shared__ __align__(16) unsigned short As[128 * 64];
    __shared__ __align__(16) unsigned short Bs[128 * 64];   // 16 KB (reused)
    __shared__ float cps[2][128][2];
    const int t = threadIdx.x;
    const int r0 = blockIdx.x * 128;
    const int lane = t & 63;
    const int wm = (t >> 6) & 1;
    const int wn = (t >> 6) >> 1;
    const int row_s = t >> 1;
    const int slot4 = (t & 1) * 4;
    const int sw = row_s & 7;

    const unsigned short* aptr = y0 + (size_t)(r0 + row_s) * O0;
    const unsigned short* bptr = Wb + (size_t)row_s * O0;
    unsigned short* asw = &As[row_s * 64];
    unsigned short* bsw = &Bs[row_s * 64];

    f32x4 zero = {0.f, 0.f, 0.f, 0.f};
    f32x4 acc[4][4];
#pragma unroll
    for (int i = 0; i < 4; ++i)
#pragma unroll
        for (int j = 0; j < 4; ++j) acc[i][j] = zero;

    for (int kt = 0; kt < O0; kt += 64) {
#pragma unroll
        for (int i = 0; i < 4; ++i) {
            const int slot = slot4 + i;
            const int ssw = slot ^ sw;
            const int c0 = kt + slot * 8;
            uint4 av = *(const uint4*)(aptr + c0);
            const float4 s0 = *(const float4*)&sc[c0];
            const float4 s1 = *(const float4*)&sc[c0 + 4];
            const float4 h0 = *(const float4*)&sh[c0];
            const float4 h1 = *(const float4*)&sh[c0 + 4];
            uint4 ov;
            {
                float v0 = b2f(av.x & 0xffff), v1 = b2f(av.x >> 16);
                ov.x = pack2(fmaxf(fmaf(v0, s0.x, h0.x), 0.f),
                             fmaxf(fmaf(v1, s0.y, h0.y), 0.f));
                float v2 = b2f(av.y & 0xffff), v3 = b2f(av.y >> 16);
                ov.y = pack2(fmaxf(fmaf(v2, s0.z, h0.z), 0.f),
                             fmaxf(fmaf(v3, s0.w, h0.w), 0.f));
                float v4 = b2f(av.z & 0xffff), v5 = b2f(av.z >> 16);
                ov.z = pack2(fmaxf(fmaf(v4, s1.x, h1.x), 0.f),
                             fmaxf(fmaf(v5, s1.y, h1.y), 0.f));
                float v6 = b2f(av.w & 0xffff), v7 = b2f(av.w >> 16);
                ov.w = pack2(fmaxf(fmaf(v6, s1.z, h1.z), 0.f),
                             fmaxf(fmaf(v7, s1.w, h1.w), 0.f));
            }
            *(uint4*)(asw + ssw * 8) = ov;
            uint4 bv = *(const uint4*)(bptr + c0);
            *(uint4*)(bsw + ssw * 8) = bv;
        }
        __syncthreads();
#pragma unroll
        for (int ks = 0; ks < 2; ++ks) {
            bf16x8 af[4], bfr[4];
#pragma unroll
            for (int fr = 0; fr < 4; ++fr) {
                const int row = wm * 64 + fr * 16 + (lane & 15);
                const int slot = (ks * 4 + (lane >> 4)) ^ (row & 7);
                af[fr] = *(const bf16x8*)&As[row * 64 + slot * 8];
            }
#pragma unroll
            for (int fc = 0; fc < 4; ++fc) {
                const int row = wn * 64 + fc * 16 + (lane & 15);
                const int slot = (ks * 4 + (lane >> 4)) ^ (row & 7);
                bfr[fc] = *(const bf16x8*)&Bs[row * 64 + slot * 8];
            }
#pragma unroll
            for (int fr = 0; fr < 4; ++fr)
#pragma unroll
                for (int fc = 0; fc < 4; ++fc)
                    acc[fr][fc] = __builtin_amdgcn_mfma_f32_16x16x32_bf16(
                        af[fr], bfr[fc], acc[fr][fc], 0, 0, 0);
        }
        __syncthreads();
    }

    // ---- column stats (from bf16-rounded values, consistent with stored y1) ----
    float bvr[4];
#pragma unroll
    for (int fc = 0; fc < 4; ++fc) {
        const int cl = wn * 64 + fc * 16 + (lane & 15);
        bvr[fc] = bias[cl];
        float s = 0.0f, q = 0.0f;
#pragma unroll
        for (int fr = 0; fr < 4; ++fr) {
#pragma unroll
            for (int j = 0; j < 4; ++j) {
                const float v = b2f(f2b(acc[fr][fc][j] + bvr[fc]));
                s += v;
                q = fmaf(v, v, q);
            }
        }
        s += __shfl_xor(s, 16); s += __shfl_xor(s, 32);
        q += __shfl_xor(q, 16); q += __shfl_xor(q, 32);
        if ((lane >> 4) == 0) { cps[wm][cl][0] = s; cps[wm][cl][1] = q; }
    }
    __syncthreads();
    if (t < 128) {
        ps[(size_t)blockIdx.x * 128 + t] = cps[0][t][0] + cps[1][t][0];
        pq[(size_t)blockIdx.x * 128 + t] = cps[0][t][1] + cps[1][t][1];
    }

    // ---- y1 store via LDS (2 phases x 64 rows x 128 cols = 16 KB in Bs) ----
#pragma unroll
    for (int p = 0; p < 2; ++p) {
        __syncthreads();
        if (wm == p) {
#pragma unroll
            for (int fc = 0; fc < 4; ++fc) {
                const int cl = wn * 64 + fc * 16 + (lane & 15);
#pragma unroll
                for (int fr = 0; fr < 4; ++fr) {
#pragma unroll
                    for (int j = 0; j < 4; ++j) {
                        const int lr = fr * 16 + (lane >> 4) * 4 + j;  // 0..63
                        Bs[lr * 128 + cl] = f2b(acc[fr][fc][j] + bvr[fc]);
                    }
                }
            }
        }
        __syncthreads();
        const int lr2 = t >> 2;                 // 0..63
        const int cb = (t & 3);                 // 4 chunk groups
#pragma unroll
        for (int i = 0; i < 4; ++i) {
            const int col = (cb + i * 4) * 8;   // 16 chunks of 8 cols
            *(uint4*)&y1[(size_t)(r0 + p * 64 + lr2) * O1 + col] =
                *(const uint4*)&Bs[lr2 * 128 + col];
        }
    }
}

// fin1: 8 blocks x 128 thr; block handles 16 channels, 8 chunks of 64 partials.
__global__ __launch_bounds__(128) void k_fin1(const float* __restrict__ ps,
                                              const float* __restrict__ pq,
                                              const float* __restrict__ gamma,
                                              const float* __restrict__ beta,
                                              float* __restrict__ sc,
                                              float* __restrict__ sh) {
    __shared__ float red[8][16][2];
    const int tid = threadIdx.x;
    const int cl = tid & 15, qr = tid >> 4;      // 0..7 chunk
    const int c = blockIdx.x * 16 + cl;
    float s = 0.0f, q = 0.0f;
    for (int bx = qr * 64; bx < qr * 64 + 64; ++bx) {
        s += ps[(size_t)bx * 128 + c];
        q += pq[(size_t)bx * 128 + c];
    }
    red[qr][cl][0] = s; red[qr][cl][1] = q;
    __syncthreads();
    if (tid < 16) {
        float ss = 0.0f, qq = 0.0f;
#pragma unroll
        for (int k = 0; k < 8; ++k) { ss += red[k][tid][0]; qq += red[k][tid][1]; }
        const int ch = blockIdx.x * 16 + tid;
        const float mean = ss * (1.0f / NROWS);
        const float var = qq * (1.0f / NROWS) - mean * mean;
        const float rs = rsqrtf(var + 1e-5f);
        const float scale = gamma[ch] * rs;
        sc[ch] = scale;
        sh[ch] = beta[ch] - mean * scale;
    }
}

// BN + ReLU: read bf16 y1, write fp32 out. 8 elems/thread.
__global__ __launch_bounds__(256) void k_bnrelu(const unsigned short* __restrict__ y1,
                                                const float* __restrict__ sc,
                                                const float* __restrict__ sh,
                                                float* __restrict__ out) {
    const int e8 = blockIdx.x * 256 + threadIdx.x;
    const int c = (e8 & 15) << 3;   // O1=128 -> col base of this 8-chunk
    const uint4 v = ((const uint4*)y1)[e8];
    float4 lo, hi;
    const float4 s0 = *(const float4*)&sc[c];
    const float4 s1 = *(const float4*)&sc[c + 4];
    const float4 h0 = *(const float4*)&sh[c];
    const float4 h1 = *(const float4*)&sh[c + 4];
    lo.x = fmaxf(fmaf(b2f(v.x & 0xffff), s0.x, h0.x), 0.0f);
    lo.y = fmaxf(fmaf(b2f(v.x >> 16),    s0.y, h0.y), 0.0f);
    lo.z = fmaxf(fmaf(b2f(v.y & 0xffff), s0.z, h0.z), 0.0f);
    lo.w = fmaxf(fmaf(b2f(v.y >> 16),    s0.w, h0.w), 0.0f);
    hi.x = fmaxf(fmaf(b2f(v.z & 0xffff), s1.x, h1.x), 0.0f);
    hi.y = fmaxf(fmaf(b2f(v.z >> 16),    s1.y, h1.y), 0.0f);
    hi.z = fmaxf(fmaf(b2f(v.w & 0xffff), s1.z, h1.z), 0.0f);
    hi.w = fmaxf(fmaf(b2f(v.w >> 16),    s1.w, h1.w), 0.0f);
    ((float4*)out)[(size_t)e8 * 2 + 0] = lo;
    ((float4*)out)[(size_t)e8 * 2 + 1] = hi;
}

// ---------------------------------------------------------------------------
extern "C" void kernel_launch(void* const* d_in, const int* in_sizes, int n_in,
                              void* d_out, int out_size, void* d_ws, size_t ws_size,
                              hipStream_t stream) {
    const float* xyz1    = (const float*)d_in[0];
    const float* xyz2    = (const float*)d_in[1];
    const float* points1 = (const float*)d_in[2];
    const float* points2 = (const float*)d_in[3];
    const float* W0      = (const float*)d_in[4];
    const float* b0      = (const float*)d_in[5];
    const float* gamma0  = (const float*)d_in[6];
    const float* beta0   = (const float*)d_in[7];
    const float* W1      = (const float*)d_in[8];
    const float* b1      = (const float*)d_in[9];
    const float* gamma1  = (const float*)d_in[10];
    const float* beta1   = (const float*)d_in[11];
    float* out = (float*)d_out;

    char* ws = (char*)d_ws;
    unsigned short* y0  = (unsigned short*)(ws + 0);            // 33,554,432 B
    unsigned short* y1b = (unsigned short*)(ws + 33554432ull);  // 16,777,216 B
    int*            idxb= (int*)           (ws + 50331648ull);  //    786,432 B
    float*          wb  = (float*)         (ws + 51118080ull);  //    786,432 B
    unsigned short* Wb0 = (unsigned short*)(ws + 51904512ull);  //    196,608 B
    unsigned short* Wb1 = (unsigned short*)(ws + 52101120ull);  //     65,536 B
    float*          ps0 = (float*)         (ws + 52166656ull);  //    524,288 B
    float*          pq0 = (float*)         (ws + 52690944ull);  //    524,288 B
    float*          ps1 = (float*)         (ws + 53215232ull);  //    262,144 B
    float*          pq1 = (float*)         (ws + 53477376ull);  //    262,144 B
    float*          sc0 = (float*)         (ws + 53739520ull);
    float*          sh0 = (float*)         (ws + 53740544ull);
    float*          sc1 = (float*)         (ws + 53741568ull);
    float*          sh1 = (float*)         (ws + 53742080ull);

    hipLaunchKernelGGL(k_knn, dim3(1024), dim3(512), 0, stream, xyz1, xyz2,
                       idxb, wb, W0, W1, Wb0, Wb1);
    hipLaunchKernelGGL(k_gemm0, dim3(NROWS / 128), dim3(512), 0, stream,
                       points1, points2, idxb, wb, Wb0, b0, y0, ps0, pq0);
    hipLaunchKernelGGL(k_fin0, dim3(8), dim3(256), 0, stream,
                       ps0, pq0, gamma0, beta0, sc0, sh0);
    hipLaunchKernelGGL(k_gemm1, dim3(NROWS / 128), dim3(256), 0, stream,
                       y0, Wb1, b1, sc0, sh0, y1b, ps1, pq1);
    hipLaunchKernelGGL(k_fin1, dim3(8), dim3(128), 0, stream,
                       ps1, pq1, gamma1, beta1, sc1, sh1);
    hipLaunchKernelGGL(k_bnrelu, dim3(NROWS * O1 / 8 / 256), dim3(256), 0, stream,
                       y1b, sc1, sh1, out);
}